// Round 9
// baseline (72.874 us; speedup 1.0000x reference)
//
#include <hip/hip_runtime.h>
#include <math.h>

constexpr int H = 2048;
constexpr int W = 4096;
constexpr int RS = W * 3;   // floats per image row

// window: 12 rows x 72 px (216 dwords used, stride 220)
constexpr int WIN_ROWS = 12;
constexpr int WIN_DW   = 216;
constexpr int WIN_STRIDE = 220;

__device__ __forceinline__ float k_inner(float t) {   // t in [0,1]
    return fmaf(fmaf(1.5f, t, -2.5f), t * t, 1.0f);
}
__device__ __forceinline__ float k_outer(float t) {   // t in [1,2]
    return fmaf(fmaf(fmaf(-0.5f, t, 2.5f), t, -4.0f), t, 2.0f);
}
__device__ __forceinline__ float cubic_w(float t) {
    float at = fabsf(t);
    if (at <= 1.0f) return k_inner(at);
    if (at < 2.0f)  return k_outer(at);
    return 0.0f;
}

__device__ __forceinline__ void row_cy(int h, const float* __restrict__ dctrl, float cy[6]) {
    float u = (float)(2 * h) / (float)(H - 1);
    float i0 = floorf(u);
    float by0 = 0.f, by1 = 0.f, by2 = 0.f;
#pragma unroll
    for (int k = -1; k < 3; ++k) {
        float tap = i0 + (float)k;
        float wt = cubic_w(u - tap);
        int tc = (int)tap;
        tc = tc < 0 ? 0 : (tc > 2 ? 2 : tc);
        if (tc == 0) by0 += wt; else if (tc == 1) by1 += wt; else by2 += wt;
    }
#pragma unroll
    for (int x = 0; x < 3; ++x) {
        cy[x]     = 5.0f * (by0 * dctrl[x]     + by1 * dctrl[3 + x]  + by2 * dctrl[6 + x]);
        cy[3 + x] = 5.0f * (by0 * dctrl[9 + x] + by1 * dctrl[12 + x] + by2 * dctrl[15 + x]);
    }
}

__device__ __forceinline__ void bx3(int w, float& b0, float& b1, float& b2) {
    float u = (float)w * (2.0f / 4095.0f);
    bool hiu = u >= 1.0f;
    float s = u - (hiu ? 1.0f : 0.0f);
    float o1 = k_outer(1.0f + s);
    float is = k_inner(s);
    float i1 = k_inner(1.0f - s);
    float o2 = k_outer(2.0f - s);
    b0 = hiu ? o1 : (o1 + is);
    b1 = hiu ? is : i1;
    b2 = hiu ? (i1 + o2) : o2;
}

// Block = 64x4 px tile (wave = one output row of 64 px).
__global__ __launch_bounds__(256)
void elastic_warp_kernel(const float* __restrict__ img,
                         const float* __restrict__ dctrl,  // (2,3,3) unscaled
                         float* __restrict__ out) {
    int x0 = blockIdx.x << 6;
    int y0 = blockIdx.y << 2;
    int t = threadIdx.x;
    int r = t >> 6;            // 0..3 tile row
    int w = x0 + (t & 63);
    int h = y0 + r;

    __shared__ float s_cy[4][6];
    __shared__ int   s_base[2];
    __shared__ int   s_flag[4];
    __shared__ float s_win[WIN_ROWS][WIN_STRIDE];   // ~10.6 KB

    if (t < 4) {
        float cy[6];
        row_cy(y0 + t, dctrl, cy);
#pragma unroll
        for (int j = 0; j < 6; ++j) s_cy[t][j] = cy[j];
        if (t == 0) {
            float b0, b1, b2; bx3(x0, b0, b1, b2);
            float d0 = cy[0]*b0 + cy[1]*b1 + cy[2]*b2;
            float d1 = cy[3]*b0 + cy[4]*b1 + cy[5]*b2;
            s_base[0] = (int)floorf((float)y0 + d0);
            s_base[1] = (int)floorf((float)x0 + d1);
        }
    }
    __syncthreads();

    float cy0 = s_cy[r][0], cy1 = s_cy[r][1], cy2 = s_cy[r][2];
    float cy3 = s_cy[r][3], cy4 = s_cy[r][4], cy5 = s_cy[r][5];
    int base_iy = s_base[0], base_ix = s_base[1];

    float bx0, bx1, bx2; bx3(w, bx0, bx1, bx2);
    float d0 = cy0*bx0 + cy1*bx1 + cy2*bx2;
    float d1 = cy3*bx0 + cy4*bx1 + cy5*bx2;

    float yy = (float)h + d0;
    float xx = (float)w + d1;
    float fly = floorf(yy), flx = floorf(xx);
    float fy = yy - fly, fx = xx - flx;
    int iy0 = (int)fly, ix0 = (int)flx;

    // window anchor (all block-uniform)
    int yb = base_iy - 2;                 // staged rows yb .. yb+11
    int xb = (base_ix - 2) & ~3;          // staged cols xb .. xb+71 (16B-aligned)

    int ry0 = iy0 - 1 - yb;               // first tap row within window
    int cxp = ix0 - 1 - xb;               // first tap col (px) within window

    bool uok = (yb >= 0) & (yb + WIN_ROWS - 1 <= H - 1) & (xb >= 0) & (xb + 71 <= W - 1);
    bool lok = (ry0 >= 0) & (ry0 <= 8) & (cxp >= 0) & (cxp <= 68);
    int wflag = __all(uok & lok);
    if ((t & 63) == 0) s_flag[t >> 6] = wflag;
    __syncthreads();
    bool fast = s_flag[0] && s_flag[1] && s_flag[2] && s_flag[3];

    // tap weights (needed by both paths)
    float wy0 = k_outer(1.0f + fy), wy1 = k_inner(fy), wy2 = k_inner(1.0f - fy), wy3 = k_outer(2.0f - fy);
    float wx0 = k_outer(1.0f + fx), wx1 = k_inner(fx), wx2 = k_inner(1.0f - fx), wx3 = k_outer(2.0f - fx);

    float acc0 = 0.f, acc1 = 0.f, acc2 = 0.f;

    if (fast) {
        // ---- cooperative stage: 12 rows x 54 float4 = 648 ----
        const float* gbase = img + yb * RS + xb * 3;
#pragma unroll
        for (int it = 0; it < 3; ++it) {
            int idx = t + (it << 8);
            if (idx < 648) {
                int row = idx / 54;
                int c4  = idx - row * 54;
                float4 v = *(const float4*)(gbase + row * RS + (c4 << 2));
                *(float4*)&s_win[row][c4 << 2] = v;
            }
        }
        __syncthreads();

        // ---- gather 4 rows x 12 floats from LDS ----
        int cxd = cxp * 3;
        float wyA[4] = {wy0, wy1, wy2, wy3};
#pragma unroll
        for (int a = 0; a < 4; ++a) {
            const float* p = &s_win[ry0 + a][cxd];
            float q0 = wyA[a] * wx0, q1 = wyA[a] * wx1, q2 = wyA[a] * wx2, q3 = wyA[a] * wx3;
            acc0 = fmaf(q0, p[0], fmaf(q1, p[3], fmaf(q2, p[6],  fmaf(q3, p[9],  acc0))));
            acc1 = fmaf(q0, p[1], fmaf(q1, p[4], fmaf(q2, p[7],  fmaf(q3, p[10], acc1))));
            acc2 = fmaf(q0, p[2], fmaf(q1, p[5], fmaf(q2, p[8],  fmaf(q3, p[11], acc2))));
        }
    } else {
        // uniform slow path: per-px clamped global gather
        float wy[4] = {wy0, wy1, wy2, wy3};
        float wx[4] = {wx0, wx1, wx2, wx3};
#pragma unroll
        for (int a = 0; a < 4; ++a) {
            int ty = iy0 + a - 1;
            ty = ty < 0 ? 0 : (ty > H - 1 ? H - 1 : ty);
            int rowoff = ty * RS;
            float ay = wy[a];
#pragma unroll
            for (int b = 0; b < 4; ++b) {
                int tx = ix0 + b - 1;
                tx = tx < 0 ? 0 : (tx > W - 1 ? W - 1 : tx);
                float wgt = ay * wx[b];
                const float* p = img + rowoff + tx * 3;
                acc0 += wgt * p[0];
                acc1 += wgt * p[1];
                acc2 += wgt * p[2];
            }
        }
    }

    int oo = (h * W + w) * 3;
    out[oo + 0] = acc0;
    out[oo + 1] = acc1;
    out[oo + 2] = acc2;
}

extern "C" void kernel_launch(void* const* d_in, const int* in_sizes, int n_in,
                              void* d_out, int out_size, void* d_ws, size_t ws_size,
                              hipStream_t stream) {
    const float* img   = (const float*)d_in[0];
    const float* dctrl = (const float*)d_in[1];
    float* out = (float*)d_out;

    dim3 grid(W / 64, H / 4);
    elastic_warp_kernel<<<grid, 256, 0, stream>>>(img, dctrl, out);
}